// Round 4
// baseline (3493.723 us; speedup 1.0000x reference)
//
#include <hip/hip_runtime.h>
#include <hip/hip_bf16.h>

// CharRNN: 2-layer LSTM LM + softmax CE on MI355X (gfx950).
// Round 4: gather/broadcast grid barrier (was 128 serialized atomics),
// MFMA CE (bf16 Wv^T), MFMA input-projection GEMM.
// dims: V=8000, B=64, T=128, H=512.

#define V_SIZE 8000
#define B_SIZE 64
#define T_SIZE 128
#define H_SIZE 512
#define NROW   (B_SIZE * T_SIZE)     // 8192
#define NG     (4 * H_SIZE)          // 2048 gate columns
#define HB     (H_SIZE * B_SIZE)     // one h-state buffer (bf16 elems)
#define RBLK   128                   // recurrence grid
#define RTH    256                   // recurrence block size

typedef __attribute__((ext_vector_type(8))) short bf16x8;
typedef __attribute__((ext_vector_type(8))) unsigned short u16x8;
typedef __attribute__((ext_vector_type(4))) float f32x4;

// ---------- bf16 helpers (raw ushort storage) ----------
__device__ __forceinline__ float bf2f(unsigned short u) {
  union { unsigned int i; float f; } x; x.i = ((unsigned int)u) << 16; return x.f;
}
__device__ __forceinline__ unsigned short f2bf(float f) {
  union { float f; unsigned int i; } x; x.f = f;
  unsigned int r = x.i + 0x7fffu + ((x.i >> 16) & 1u);
  return (unsigned short)(r >> 16);
}
__device__ __forceinline__ float sigf(float v) { return 1.f / (1.f + expf(-v)); }

// ---------------- zero ----------------
__global__ void zero_k(float* __restrict__ p, int n) {
  int i = blockIdx.x * 256 + threadIdx.x;
  if (i < n) p[i] = 0.f;
}

// ---------------- embedding gather -> bf16 x [8192 rows=t*64+b][512] ----------------
__global__ __launch_bounds__(256) void xgather_k(const int* __restrict__ ids,
                                                 const float* __restrict__ emb,
                                                 unsigned short* __restrict__ xb) {
  int g = blockIdx.x * 256 + threadIdx.x;   // 8192 rows x 64 chunks of 8
  int r = g >> 6, c = g & 63;
  int t = r >> 6, b = r & 63;
  int id = ids[(size_t)b * T_SIZE + t];
  const float4* s4 = reinterpret_cast<const float4*>(emb + (size_t)id * H_SIZE + c * 8);
  float4 v0 = s4[0], v1 = s4[1];
  u16x8 o;
  o[0] = f2bf(v0.x); o[1] = f2bf(v0.y); o[2] = f2bf(v0.z); o[3] = f2bf(v0.w);
  o[4] = f2bf(v1.x); o[5] = f2bf(v1.y); o[6] = f2bf(v1.z); o[7] = f2bf(v1.w);
  *reinterpret_cast<u16x8*>(xb + (size_t)r * H_SIZE + c * 8) = o;
}

// ---------------- f32 [K][N] -> bf16 [N][K] transpose (64x64 tiles) ----------------
// dst row length fixed = 512. grid = (K/64) * n_tiles, n_tiles = N/64.
__global__ __launch_bounds__(256) void trans_k(const float* __restrict__ src,
                                               unsigned short* __restrict__ dst,
                                               int src_ld, int n_tiles) {
  __shared__ float tile[64][65];
  const int tid = threadIdx.x;
  const int kt = blockIdx.x / n_tiles, nt = blockIdx.x % n_tiles;
#pragma unroll
  for (int q = 0; q < 16; ++q) {
    int f = tid + 256 * q;
    int r = f >> 6, c = f & 63;
    tile[r][c] = src[(size_t)(kt * 64 + r) * src_ld + nt * 64 + c];
  }
  __syncthreads();
#pragma unroll
  for (int q = 0; q < 2; ++q) {
    int u = tid + 256 * q;
    int n = u >> 3, kg = u & 7;
    u16x8 o;
#pragma unroll
    for (int e = 0; e < 8; ++e) o[e] = f2bf(tile[kg * 8 + e][n]);
    *reinterpret_cast<u16x8*>(dst + (size_t)(nt * 64 + n) * 512 + kt * 64 + kg * 8) = o;
  }
}

// ---------------- G1 = x @ W1x + b1 (MFMA), bf16 out [t][b][2048] ----------------
// grid 256: bx = t*2 + nhalf. 4 waves x 16 rows; A register-resident.
__global__ __launch_bounds__(256) void gemm1mm_k(const unsigned short* __restrict__ xb,
                                                 const unsigned short* __restrict__ W1b,
                                                 const float* __restrict__ b1,
                                                 unsigned short* __restrict__ G1) {
  const int tid = threadIdx.x;
  const int t = blockIdx.x >> 1, half = blockIdx.x & 1;
  const int w = tid >> 6, l = tid & 63;
  const int m0 = w * 16;
  const int kof = (l >> 4) * 8;
  bf16x8 av[16];
#pragma unroll
  for (int ks = 0; ks < 16; ++ks)
    av[ks] = *reinterpret_cast<const bf16x8*>(
        xb + ((size_t)t * 64 + m0 + (l & 15)) * H_SIZE + ks * 32 + kof);
  const int crow0 = m0 + ((l >> 4) << 2);
  for (int ct = 0; ct < 64; ++ct) {
    int vc = half * 1024 + ct * 16 + (l & 15);
    f32x4 acc = {0.f, 0.f, 0.f, 0.f};
#pragma unroll
    for (int ks = 0; ks < 16; ++ks) {
      bf16x8 bvv = *reinterpret_cast<const bf16x8*>(
          W1b + (size_t)vc * 512 + ks * 32 + kof);
      acc = __builtin_amdgcn_mfma_f32_16x16x32_bf16(av[ks], bvv, acc, 0, 0, 0);
    }
    float bb = b1[vc];
#pragma unroll
    for (int r = 0; r < 4; ++r)
      G1[((size_t)t * 64 + crow0 + r) * NG + vc] = f2bf(acc[r] + bb);
  }
}

// ---------------- persistent MFMA 2-layer LSTM recurrence ----------------
// Blocks 0..63: layer 1 (t=p). Blocks 64..127: layer 2 (t=p-1).
// Gather/broadcast grid barrier via flags[128] + go word (flags[128]).
__global__ __launch_bounds__(RTH) void recur_k(
    const float* __restrict__ W1, const float* __restrict__ W2,
    const float* __restrict__ b2, const unsigned short* __restrict__ G1,
    unsigned short* __restrict__ h1g, unsigned short* __restrict__ h2g,
    unsigned short* __restrict__ outs, int* __restrict__ flags)
{
  __shared__ short wlds[2 * 32 * 64 * 8];   // 64 KB (L1 uses half)
  __shared__ float gbuf[64][32];            // 8 KB

  const int tid  = threadIdx.x;
  const int bid  = blockIdx.x;
  const bool isL2 = (bid >= 64);
  const int h0   = (isL2 ? bid - 64 : bid) * 8;
  const int w    = tid >> 6, l = tid & 63;
  const int NK   = isL2 ? 32 : 16;          // ksteps per phase

  // ---- one-time weight preload, bf16 in B-frag order ----
  {
    const float* Wsrc = isL2 ? W2 : (W1 + (size_t)H_SIZE * NG);
    for (int idx = tid; idx < 2 * NK * 64; idx += RTH) {
      int lane = idx & 63;
      int ks   = (idx >> 6) % NK;
      int ng   = (idx >> 6) / NK;
      int n    = lane & 15;
      int col  = (n & 3) * H_SIZE + h0 + ng * 4 + (n >> 2);
      int kb   = ks * 32 + (lane >> 4) * 8;
      short* dst = &wlds[((size_t)(ng * NK + ks) * 64 + lane) * 8];
#pragma unroll
      for (int e = 0; e < 8; ++e)
        dst[e] = (short)f2bf(Wsrc[(size_t)(kb + e) * NG + col]);
    }
  }

  const int pb = tid >> 2, pq = tid & 3;
  float cst[2] = {0.f, 0.f};
  float bias2[2][4];
  if (isL2) {
#pragma unroll
    for (int hh = 0; hh < 2; ++hh)
#pragma unroll
      for (int g = 0; g < 4; ++g)
        bias2[hh][g] = b2[g * H_SIZE + h0 + pq + hh * 4];
  }
  __syncthreads();

  for (int p = 0; p <= T_SIZE; ++p) {
    const bool active = isL2 ? (p >= 1) : (p < T_SIZE);
    if (active) {
      const int t = isL2 ? p - 1 : p;
      const unsigned short* asrc1 = isL2 ? (h1g + (size_t)(t & 1) * HB)
                                         : (h1g + (size_t)((p + 1) & 1) * HB);
      const unsigned short* asrc2 = isL2 ? (h2g + (size_t)((t + 1) & 1) * HB)
                                         : asrc1;
      const int arow = w * 16 + (l & 15);
      const unsigned short* a1 = asrc1 + (size_t)arow * H_SIZE + (l >> 4) * 8;
      const unsigned short* a2 = asrc2 + (size_t)arow * H_SIZE + (l >> 4) * 8;

      f32x4 acc0 = {0.f, 0.f, 0.f, 0.f};
      f32x4 acc1 = {0.f, 0.f, 0.f, 0.f};
      if (!isL2) {
#pragma unroll
        for (int ks = 0; ks < 16; ++ks) {
          bf16x8 av = *reinterpret_cast<const bf16x8*>(a1 + ks * 32);
          bf16x8 bv0 = *reinterpret_cast<const bf16x8*>(&wlds[((size_t)(0 * 16 + ks) * 64 + l) * 8]);
          bf16x8 bv1 = *reinterpret_cast<const bf16x8*>(&wlds[((size_t)(1 * 16 + ks) * 64 + l) * 8]);
          acc0 = __builtin_amdgcn_mfma_f32_16x16x32_bf16(av, bv0, acc0, 0, 0, 0);
          acc1 = __builtin_amdgcn_mfma_f32_16x16x32_bf16(av, bv1, acc1, 0, 0, 0);
        }
      } else {
#pragma unroll
        for (int ks = 0; ks < 32; ++ks) {
          const unsigned short* ap = (ks < 16) ? (a1 + ks * 32) : (a2 + (ks - 16) * 32);
          bf16x8 av = *reinterpret_cast<const bf16x8*>(ap);
          bf16x8 bv0 = *reinterpret_cast<const bf16x8*>(&wlds[((size_t)(0 * 32 + ks) * 64 + l) * 8]);
          bf16x8 bv1 = *reinterpret_cast<const bf16x8*>(&wlds[((size_t)(1 * 32 + ks) * 64 + l) * 8]);
          acc0 = __builtin_amdgcn_mfma_f32_16x16x32_bf16(av, bv0, acc0, 0, 0, 0);
          acc1 = __builtin_amdgcn_mfma_f32_16x16x32_bf16(av, bv1, acc1, 0, 0, 0);
        }
      }

      {
        const int crow = w * 16 + ((l >> 4) << 2);
        const int ccol = l & 15;
#pragma unroll
        for (int r = 0; r < 4; ++r) {
          gbuf[crow + r][ccol]      = acc0[r];
          gbuf[crow + r][16 + ccol] = acc1[r];
        }
      }
      __syncthreads();

#pragma unroll
      for (int hh = 0; hh < 2; ++hh) {
        const int hl = pq + hh * 4;
        const int ng = hl >> 2, jj = hl & 3;
        float g[4];
#pragma unroll
        for (int gg = 0; gg < 4; ++gg) g[gg] = gbuf[pb][ng * 16 + jj * 4 + gg];
        if (!isL2) {
#pragma unroll
          for (int gg = 0; gg < 4; ++gg)
            g[gg] += bf2f(G1[((size_t)t * 64 + pb) * NG + gg * H_SIZE + h0 + hl]);
        } else {
#pragma unroll
          for (int gg = 0; gg < 4; ++gg) g[gg] += bias2[hh][gg];
        }
        float cn = cst[hh] * sigf(g[2]) + sigf(g[0]) * tanhf(g[1]);
        float hn = tanhf(cn) * sigf(g[3]);
        cst[hh] = cn;
        unsigned short hb = f2bf(hn);
        if (!isL2) {
          h1g[(size_t)(p & 1) * HB + (size_t)pb * H_SIZE + h0 + hl] = hb;
        } else {
          h2g[(size_t)(t & 1) * HB + (size_t)pb * H_SIZE + h0 + hl] = hb;
          outs[((size_t)t * 64 + pb) * H_SIZE + h0 + hl] = hb;
        }
      }
    }

    // ---------------- gather/broadcast grid barrier ----------------
    __syncthreads();
    if (tid == 0) {
      __threadfence();
      __hip_atomic_store(&flags[bid], p + 1, __ATOMIC_RELEASE, __HIP_MEMORY_SCOPE_AGENT);
    }
    if (bid == 0) {
      if (tid < RBLK) {
        while (__hip_atomic_load(&flags[tid], __ATOMIC_ACQUIRE, __HIP_MEMORY_SCOPE_AGENT) < p + 1)
          __builtin_amdgcn_s_sleep(1);
      }
      __syncthreads();
      if (tid == 0)
        __hip_atomic_store(&flags[RBLK], p + 1, __ATOMIC_RELEASE, __HIP_MEMORY_SCOPE_AGENT);
    }
    if (tid == 0) {
      while (__hip_atomic_load(&flags[RBLK], __ATOMIC_ACQUIRE, __HIP_MEMORY_SCOPE_AGENT) < p + 1)
        __builtin_amdgcn_s_sleep(1);
      __threadfence();
    }
    __syncthreads();
  }
}

// ---------------- MFMA fused logits + online logsumexp + target capture ----------------
// grid 256: bx = t*2 + vhalf (4000 cols each). 4 waves x 16 rows. A in registers.
// Writes per-(t,half,row) partial (max, sumexp, target-logit-sum).
__global__ __launch_bounds__(256) void ce_mfma_k(const unsigned short* __restrict__ outs,
                                                 const unsigned short* __restrict__ Wvb,
                                                 const float* __restrict__ bvb,
                                                 const int* __restrict__ tgts,
                                                 float* __restrict__ pmx,
                                                 float* __restrict__ psm,
                                                 float* __restrict__ ptg) {
  const int tid = threadIdx.x;
  const int t = blockIdx.x >> 1, half = blockIdx.x & 1;
  const int w = tid >> 6, l = tid & 63;
  const int m0 = w * 16;
  const int kof = (l >> 4) * 8;
  bf16x8 av[16];
#pragma unroll
  for (int ks = 0; ks < 16; ++ks)
    av[ks] = *reinterpret_cast<const bf16x8*>(
        outs + ((size_t)t * 64 + m0 + (l & 15)) * H_SIZE + ks * 32 + kof);
  int lbl[4];
#pragma unroll
  for (int r = 0; r < 4; ++r)
    lbl[r] = tgts[(size_t)(m0 + ((l >> 4) << 2) + r) * T_SIZE + t];

  float mx[4] = {-1e30f, -1e30f, -1e30f, -1e30f};
  float sm[4] = {0.f, 0.f, 0.f, 0.f};
  float tg[4] = {0.f, 0.f, 0.f, 0.f};

  for (int ct = 0; ct < 250; ++ct) {
    int vc = half * 4000 + ct * 16 + (l & 15);
    f32x4 acc = {0.f, 0.f, 0.f, 0.f};
#pragma unroll
    for (int ks = 0; ks < 16; ++ks) {
      bf16x8 bvv = *reinterpret_cast<const bf16x8*>(
          Wvb + (size_t)vc * 512 + ks * 32 + kof);
      acc = __builtin_amdgcn_mfma_f32_16x16x32_bf16(av[ks], bvv, acc, 0, 0, 0);
    }
    float bb = bvb[vc];
#pragma unroll
    for (int r = 0; r < 4; ++r) {
      float lg = acc[r] + bb;
      tg[r] += (vc == lbl[r]) ? lg : 0.f;
      if (lg <= mx[r]) {
        sm[r] += __expf(lg - mx[r]);
      } else {
        sm[r] = sm[r] * __expf(mx[r] - lg) + 1.f;
        mx[r] = lg;
      }
    }
  }

  // merge across the 16 col-lanes (xor of low 4 lane bits)
#pragma unroll
  for (int off = 1; off <= 8; off <<= 1) {
#pragma unroll
    for (int r = 0; r < 4; ++r) {
      float om = __shfl_xor(mx[r], off, 64);
      float os = __shfl_xor(sm[r], off, 64);
      float ot = __shfl_xor(tg[r], off, 64);
      float nm = fmaxf(mx[r], om);
      sm[r] = sm[r] * __expf(mx[r] - nm) + os * __expf(om - nm);
      mx[r] = nm;
      tg[r] += ot;
    }
  }
  if ((l & 15) == 0) {
    int idx = (t * 2 + half) * 64 + m0 + ((l >> 4) << 2);
#pragma unroll
    for (int r = 0; r < 4; ++r) {
      pmx[idx + r] = mx[r]; psm[idx + r] = sm[r]; ptg[idx + r] = tg[r];
    }
  }
}

// ---------------- merge halves, per-row loss, sum ----------------
__global__ __launch_bounds__(256) void cemerge_k(const float* __restrict__ pmx,
                                                 const float* __restrict__ psm,
                                                 const float* __restrict__ ptg,
                                                 float* __restrict__ accum) {
  int g = blockIdx.x * 256 + threadIdx.x;   // 0..8191
  int t = g >> 6, row = g & 63;
  int i0 = (t * 2) * 64 + row, i1 = (t * 2 + 1) * 64 + row;
  float m0 = pmx[i0], m1 = pmx[i1];
  float M = fmaxf(m0, m1);
  float S = psm[i0] * __expf(m0 - M) + psm[i1] * __expf(m1 - M);
  float loss = M + logf(S) - (ptg[i0] + ptg[i1]);
#pragma unroll
  for (int off = 32; off >= 1; off >>= 1)
    loss += __shfl_xor(loss, off, 64);
  if ((threadIdx.x & 63) == 0) atomicAdd(accum, loss);
}

__global__ void finish_k(const float* __restrict__ accum, float* __restrict__ out) {
  out[0] = accum[0] * (1.f / (float)NROW);
}

// ---------------- launcher ----------------
extern "C" void kernel_launch(void* const* d_in, const int* in_sizes, int n_in,
                              void* d_out, int out_size, void* d_ws, size_t ws_size,
                              hipStream_t stream) {
  const int*   ids  = (const int*)  d_in[0];
  const int*   tgts = (const int*)  d_in[1];
  const float* emb  = (const float*)d_in[2];
  const float* W1   = (const float*)d_in[3];
  const float* b1   = (const float*)d_in[4];
  const float* W2   = (const float*)d_in[5];
  const float* b2   = (const float*)d_in[6];
  const float* Wv   = (const float*)d_in[7];
  const float* bv   = (const float*)d_in[8];
  float* out = (float*)d_out;

  // ws layout (bytes), xb and Wvb share one region (xb dead before wvtrans):
  char* ws = (char*)d_ws;
  unsigned short* G1    = (unsigned short*)(ws);                 // 33,554,432
  unsigned short* outsb = (unsigned short*)(ws + 33554432);      //  8,388,608
  unsigned short* h1g   = (unsigned short*)(ws + 41943040);      //    131,072
  unsigned short* h2g   = (unsigned short*)(ws + 42074112);      //    131,072
  unsigned short* xb    = (unsigned short*)(ws + 42205184);      //  8,388,608 (union)
  unsigned short* Wvb   = (unsigned short*)(ws + 42205184);      //  8,192,000 (union)
  unsigned short* W1b   = (unsigned short*)(ws + 50593792);      //  2,097,152
  float*          pmx   = (float*)         (ws + 52690944);      //     65,536
  float*          psm   = (float*)         (ws + 52756480);      //     65,536
  float*          ptg   = (float*)         (ws + 52822016);      //     65,536
  float*          accum = (float*)         (ws + 52887552);      //          4
  int*            flags = (int*)           (ws + 52887556);      //        516

  // zero h-states (65,536 f32) and accum+flags (130 f32)
  zero_k<<<256, 256, 0, stream>>>((float*)h1g, 65536);
  zero_k<<<1, 256, 0, stream>>>(accum, 130);

  xgather_k<<<2048, 256, 0, stream>>>(ids, emb, xb);
  trans_k<<<256, 256, 0, stream>>>(W1, W1b, NG, 32);         // W1[0:512,:] -> W1b
  gemm1mm_k<<<256, 256, 0, stream>>>(xb, W1b, b1, G1);
  trans_k<<<1000, 256, 0, stream>>>(Wv, Wvb, V_SIZE, 125);   // Wv -> Wvb (after gemm1: xb dead)

  {
    void* args[] = { (void*)&W1, (void*)&W2, (void*)&b2, (void*)&G1,
                     (void*)&h1g, (void*)&h2g, (void*)&outsb, (void*)&flags };
    hipError_t e = hipLaunchCooperativeKernel((const void*)recur_k,
                                              dim3(RBLK), dim3(RTH),
                                              args, 0, stream);
    if (e != hipSuccess) {
      recur_k<<<dim3(RBLK), dim3(RTH), 0, stream>>>(W1, W2, b2, G1, h1g, h2g,
                                                    outsb, flags);
    }
  }

  ce_mfma_k<<<256, 256, 0, stream>>>(outsb, Wvb, bv, tgts, pmx, psm, ptg);
  cemerge_k<<<32, 256, 0, stream>>>(pmx, psm, ptg, accum);
  finish_k<<<1, 1, 0, stream>>>(accum, out);
}

// Round 5
// 2059.527 us; speedup vs baseline: 1.6964x; 1.6964x over previous
//
#include <hip/hip_runtime.h>
#include <hip/hip_bf16.h>

// CharRNN: 2-layer LSTM LM + softmax CE on MI355X (gfx950).
// Round 5: fence-free recurrence. All cross-block h-state via agent-scope
// relaxed atomics (sc1 -> MALL-coherent, L2-bypass); barrier = flag store +
// distributed poll, no __threadfence (no L2 writeback) anywhere in the loop.
// dims: V=8000, B=64, T=128, H=512.

#define V_SIZE 8000
#define B_SIZE 64
#define T_SIZE 128
#define H_SIZE 512
#define NROW   (B_SIZE * T_SIZE)     // 8192
#define NG     (4 * H_SIZE)          // 2048 gate columns
#define HB     (H_SIZE * B_SIZE)     // one h-state buffer (bf16 elems)
#define RBLK   128                   // recurrence grid
#define RTH    256                   // recurrence block size

typedef __attribute__((ext_vector_type(8))) short bf16x8;
typedef __attribute__((ext_vector_type(8))) unsigned short u16x8;
typedef __attribute__((ext_vector_type(4))) float f32x4;

// ---------- bf16 helpers (raw ushort storage) ----------
__device__ __forceinline__ float bf2f(unsigned short u) {
  union { unsigned int i; float f; } x; x.i = ((unsigned int)u) << 16; return x.f;
}
__device__ __forceinline__ unsigned short f2bf(float f) {
  union { float f; unsigned int i; } x; x.f = f;
  unsigned int r = x.i + 0x7fffu + ((x.i >> 16) & 1u);
  return (unsigned short)(r >> 16);
}
__device__ __forceinline__ float sigf(float v) { return 1.f / (1.f + expf(-v)); }

// agent-scope (MALL-coherent, L2-bypassing) 16B A-fragment load as 2x u64
__device__ __forceinline__ bf16x8 aload16(const unsigned short* p) {
  unsigned long long lo = __hip_atomic_load((const unsigned long long*)p,
                                            __ATOMIC_RELAXED, __HIP_MEMORY_SCOPE_AGENT);
  unsigned long long hi = __hip_atomic_load((const unsigned long long*)(p + 4),
                                            __ATOMIC_RELAXED, __HIP_MEMORY_SCOPE_AGENT);
  union { unsigned long long v[2]; bf16x8 b; } u;
  u.v[0] = lo; u.v[1] = hi;
  return u.b;
}

// ---------------- zero ----------------
__global__ void zero_k(float* __restrict__ p, int n) {
  int i = blockIdx.x * 256 + threadIdx.x;
  if (i < n) p[i] = 0.f;
}

// ---------------- embedding gather -> bf16 x [8192 rows=t*64+b][512] ----------------
__global__ __launch_bounds__(256) void xgather_k(const int* __restrict__ ids,
                                                 const float* __restrict__ emb,
                                                 unsigned short* __restrict__ xb) {
  int g = blockIdx.x * 256 + threadIdx.x;   // 8192 rows x 64 chunks of 8
  int r = g >> 6, c = g & 63;
  int t = r >> 6, b = r & 63;
  int id = ids[(size_t)b * T_SIZE + t];
  const float4* s4 = reinterpret_cast<const float4*>(emb + (size_t)id * H_SIZE + c * 8);
  float4 v0 = s4[0], v1 = s4[1];
  u16x8 o;
  o[0] = f2bf(v0.x); o[1] = f2bf(v0.y); o[2] = f2bf(v0.z); o[3] = f2bf(v0.w);
  o[4] = f2bf(v1.x); o[5] = f2bf(v1.y); o[6] = f2bf(v1.z); o[7] = f2bf(v1.w);
  *reinterpret_cast<u16x8*>(xb + (size_t)r * H_SIZE + c * 8) = o;
}

// ---------------- f32 [K][N] -> bf16 [N][K] transpose (64x64 tiles) ----------------
__global__ __launch_bounds__(256) void trans_k(const float* __restrict__ src,
                                               unsigned short* __restrict__ dst,
                                               int src_ld, int n_tiles) {
  __shared__ float tile[64][65];
  const int tid = threadIdx.x;
  const int kt = blockIdx.x / n_tiles, nt = blockIdx.x % n_tiles;
#pragma unroll
  for (int q = 0; q < 16; ++q) {
    int f = tid + 256 * q;
    int r = f >> 6, c = f & 63;
    tile[r][c] = src[(size_t)(kt * 64 + r) * src_ld + nt * 64 + c];
  }
  __syncthreads();
#pragma unroll
  for (int q = 0; q < 2; ++q) {
    int u = tid + 256 * q;
    int n = u >> 3, kg = u & 7;
    u16x8 o;
#pragma unroll
    for (int e = 0; e < 8; ++e) o[e] = f2bf(tile[kg * 8 + e][n]);
    *reinterpret_cast<u16x8*>(dst + (size_t)(nt * 64 + n) * 512 + kt * 64 + kg * 8) = o;
  }
}

// ---------------- G1 = x @ W1x + b1 (MFMA), bf16 out [t][b][2048] ----------------
__global__ __launch_bounds__(256) void gemm1mm_k(const unsigned short* __restrict__ xb,
                                                 const unsigned short* __restrict__ W1b,
                                                 const float* __restrict__ b1,
                                                 unsigned short* __restrict__ G1) {
  const int tid = threadIdx.x;
  const int t = blockIdx.x >> 1, half = blockIdx.x & 1;
  const int w = tid >> 6, l = tid & 63;
  const int m0 = w * 16;
  const int kof = (l >> 4) * 8;
  bf16x8 av[16];
#pragma unroll
  for (int ks = 0; ks < 16; ++ks)
    av[ks] = *reinterpret_cast<const bf16x8*>(
        xb + ((size_t)t * 64 + m0 + (l & 15)) * H_SIZE + ks * 32 + kof);
  const int crow0 = m0 + ((l >> 4) << 2);
  for (int ct = 0; ct < 64; ++ct) {
    int vc = half * 1024 + ct * 16 + (l & 15);
    f32x4 acc = {0.f, 0.f, 0.f, 0.f};
#pragma unroll
    for (int ks = 0; ks < 16; ++ks) {
      bf16x8 bvv = *reinterpret_cast<const bf16x8*>(
          W1b + (size_t)vc * 512 + ks * 32 + kof);
      acc = __builtin_amdgcn_mfma_f32_16x16x32_bf16(av[ks], bvv, acc, 0, 0, 0);
    }
    float bb = b1[vc];
#pragma unroll
    for (int r = 0; r < 4; ++r)
      G1[((size_t)t * 64 + crow0 + r) * NG + vc] = f2bf(acc[r] + bb);
  }
}

// ---------------- persistent MFMA 2-layer LSTM recurrence (fence-free) ----------------
// Blocks 0..63: layer 1 (t=p). Blocks 64..127: layer 2 (t=p-1).
// h-state: bf16 [b][512], exchanged ONLY via agent-scope relaxed atomics.
// Barrier: flags[bid*16]=p+1 (relaxed store after __syncthreads-drain);
// 128 threads/block each poll one flag; no fences in the loop.
__global__ __launch_bounds__(RTH) void recur_k(
    const float* __restrict__ W1, const float* __restrict__ W2,
    const float* __restrict__ b2, const unsigned short* __restrict__ G1,
    unsigned short* __restrict__ h1g, unsigned short* __restrict__ h2g,
    unsigned short* __restrict__ outs, int* __restrict__ flags)
{
  __shared__ short wlds[2 * 32 * 64 * 8];   // 64 KB (L1 uses half)
  __shared__ float gbuf[64][32];            // 8 KB

  const int tid  = threadIdx.x;
  const int bid  = blockIdx.x;
  const bool isL2 = (bid >= 64);
  const int h0   = (isL2 ? bid - 64 : bid) * 8;
  const int w    = tid >> 6, l = tid & 63;
  const int NK   = isL2 ? 32 : 16;          // ksteps per phase

  // ---- one-time weight preload, bf16 in B-frag order ----
  {
    const float* Wsrc = isL2 ? W2 : (W1 + (size_t)H_SIZE * NG);
    for (int idx = tid; idx < 2 * NK * 64; idx += RTH) {
      int lane = idx & 63;
      int ks   = (idx >> 6) % NK;
      int ng   = (idx >> 6) / NK;
      int n    = lane & 15;
      int col  = (n & 3) * H_SIZE + h0 + ng * 4 + (n >> 2);
      int kb   = ks * 32 + (lane >> 4) * 8;
      short* dst = &wlds[((size_t)(ng * NK + ks) * 64 + lane) * 8];
#pragma unroll
      for (int e = 0; e < 8; ++e)
        dst[e] = (short)f2bf(Wsrc[(size_t)(kb + e) * NG + col]);
    }
  }

  // pointwise mapping: thread = pb*4+pq handles (b=pb, cols h0+2pq, h0+2pq+1)
  const int pb = tid >> 2, pq = tid & 3;
  float cst[2] = {0.f, 0.f};
  float bias2[2][4];
  if (isL2) {
#pragma unroll
    for (int hh = 0; hh < 2; ++hh)
#pragma unroll
      for (int g = 0; g < 4; ++g)
        bias2[hh][g] = b2[g * H_SIZE + h0 + 2 * pq + hh];
  }
  __syncthreads();

  for (int p = 0; p <= T_SIZE; ++p) {
    const bool active = isL2 ? (p >= 1) : (p < T_SIZE);
    if (active) {
      const int t = isL2 ? p - 1 : p;
      const unsigned short* asrc1 = isL2 ? (h1g + (size_t)(t & 1) * HB)
                                         : (h1g + (size_t)((p + 1) & 1) * HB);
      const unsigned short* asrc2 = isL2 ? (h2g + (size_t)((t + 1) & 1) * HB)
                                         : asrc1;
      const int arow = w * 16 + (l & 15);
      const unsigned short* a1 = asrc1 + (size_t)arow * H_SIZE + (l >> 4) * 8;
      const unsigned short* a2 = asrc2 + (size_t)arow * H_SIZE + (l >> 4) * 8;

      f32x4 acc0 = {0.f, 0.f, 0.f, 0.f};
      f32x4 acc1 = {0.f, 0.f, 0.f, 0.f};
      if (!isL2) {
#pragma unroll
        for (int ks = 0; ks < 16; ++ks) {
          bf16x8 av = aload16(a1 + ks * 32);
          bf16x8 bv0 = *reinterpret_cast<const bf16x8*>(&wlds[((size_t)(0 * 16 + ks) * 64 + l) * 8]);
          bf16x8 bv1 = *reinterpret_cast<const bf16x8*>(&wlds[((size_t)(1 * 16 + ks) * 64 + l) * 8]);
          acc0 = __builtin_amdgcn_mfma_f32_16x16x32_bf16(av, bv0, acc0, 0, 0, 0);
          acc1 = __builtin_amdgcn_mfma_f32_16x16x32_bf16(av, bv1, acc1, 0, 0, 0);
        }
      } else {
#pragma unroll
        for (int ks = 0; ks < 32; ++ks) {
          const unsigned short* ap = (ks < 16) ? (a1 + ks * 32) : (a2 + (ks - 16) * 32);
          bf16x8 av = aload16(ap);
          bf16x8 bv0 = *reinterpret_cast<const bf16x8*>(&wlds[((size_t)(0 * 32 + ks) * 64 + l) * 8]);
          bf16x8 bv1 = *reinterpret_cast<const bf16x8*>(&wlds[((size_t)(1 * 32 + ks) * 64 + l) * 8]);
          acc0 = __builtin_amdgcn_mfma_f32_16x16x32_bf16(av, bv0, acc0, 0, 0, 0);
          acc1 = __builtin_amdgcn_mfma_f32_16x16x32_bf16(av, bv1, acc1, 0, 0, 0);
        }
      }

      {
        const int crow = w * 16 + ((l >> 4) << 2);
        const int ccol = l & 15;
#pragma unroll
        for (int r = 0; r < 4; ++r) {
          gbuf[crow + r][ccol]      = acc0[r];
          gbuf[crow + r][16 + ccol] = acc1[r];
        }
      }
      __syncthreads();

      // pointwise: two adjacent h-cols per thread -> one packed u32 atomic store
      unsigned short hbv[2];
#pragma unroll
      for (int hh = 0; hh < 2; ++hh) {
        const int hl = 2 * pq + hh;
        const int ng = hl >> 2, jj = hl & 3;
        float g[4];
#pragma unroll
        for (int gg = 0; gg < 4; ++gg) g[gg] = gbuf[pb][ng * 16 + jj * 4 + gg];
        if (!isL2) {
#pragma unroll
          for (int gg = 0; gg < 4; ++gg)
            g[gg] += bf2f(G1[((size_t)t * 64 + pb) * NG + gg * H_SIZE + h0 + hl]);
        } else {
#pragma unroll
          for (int gg = 0; gg < 4; ++gg) g[gg] += bias2[hh][gg];
        }
        float cn = cst[hh] * sigf(g[2]) + sigf(g[0]) * tanhf(g[1]);
        float hn = tanhf(cn) * sigf(g[3]);
        cst[hh] = cn;
        hbv[hh] = f2bf(hn);
      }
      unsigned int pack = (unsigned int)hbv[0] | ((unsigned int)hbv[1] << 16);
      if (!isL2) {
        unsigned int* dst = (unsigned int*)(h1g + (size_t)(p & 1) * HB
                                            + (size_t)pb * H_SIZE + h0 + 2 * pq);
        __hip_atomic_store(dst, pack, __ATOMIC_RELAXED, __HIP_MEMORY_SCOPE_AGENT);
      } else {
        unsigned int* dst = (unsigned int*)(h2g + (size_t)(t & 1) * HB
                                            + (size_t)pb * H_SIZE + h0 + 2 * pq);
        __hip_atomic_store(dst, pack, __ATOMIC_RELAXED, __HIP_MEMORY_SCOPE_AGENT);
        *(unsigned int*)(outs + ((size_t)t * 64 + pb) * H_SIZE + h0 + 2 * pq) = pack;
      }
    }

    // ---------------- fence-free grid barrier ----------------
    // __syncthreads drains each thread's vmem (sc1 stores complete at MALL).
    __syncthreads();
    if (tid == 0)
      __hip_atomic_store(&flags[bid * 16], p + 1, __ATOMIC_RELAXED,
                         __HIP_MEMORY_SCOPE_AGENT);
    if (tid < RBLK) {
      while (__hip_atomic_load(&flags[tid * 16], __ATOMIC_RELAXED,
                               __HIP_MEMORY_SCOPE_AGENT) < p + 1)
        __builtin_amdgcn_s_sleep(1);
    }
    __syncthreads();
  }
}

// ---------------- MFMA fused logits + online logsumexp + target capture ----------------
__global__ __launch_bounds__(256) void ce_mfma_k(const unsigned short* __restrict__ outs,
                                                 const unsigned short* __restrict__ Wvb,
                                                 const float* __restrict__ bvb,
                                                 const int* __restrict__ tgts,
                                                 float* __restrict__ pmx,
                                                 float* __restrict__ psm,
                                                 float* __restrict__ ptg) {
  const int tid = threadIdx.x;
  const int t = blockIdx.x >> 1, half = blockIdx.x & 1;
  const int w = tid >> 6, l = tid & 63;
  const int m0 = w * 16;
  const int kof = (l >> 4) * 8;
  bf16x8 av[16];
#pragma unroll
  for (int ks = 0; ks < 16; ++ks)
    av[ks] = *reinterpret_cast<const bf16x8*>(
        outs + ((size_t)t * 64 + m0 + (l & 15)) * H_SIZE + ks * 32 + kof);
  int lbl[4];
#pragma unroll
  for (int r = 0; r < 4; ++r)
    lbl[r] = tgts[(size_t)(m0 + ((l >> 4) << 2) + r) * T_SIZE + t];

  float mx[4] = {-1e30f, -1e30f, -1e30f, -1e30f};
  float sm[4] = {0.f, 0.f, 0.f, 0.f};
  float tg[4] = {0.f, 0.f, 0.f, 0.f};

  for (int ct = 0; ct < 250; ++ct) {
    int vc = half * 4000 + ct * 16 + (l & 15);
    f32x4 acc = {0.f, 0.f, 0.f, 0.f};
#pragma unroll
    for (int ks = 0; ks < 16; ++ks) {
      bf16x8 bvv = *reinterpret_cast<const bf16x8*>(
          Wvb + (size_t)vc * 512 + ks * 32 + kof);
      acc = __builtin_amdgcn_mfma_f32_16x16x32_bf16(av[ks], bvv, acc, 0, 0, 0);
    }
    float bb = bvb[vc];
#pragma unroll
    for (int r = 0; r < 4; ++r) {
      float lg = acc[r] + bb;
      tg[r] += (vc == lbl[r]) ? lg : 0.f;
      if (lg <= mx[r]) {
        sm[r] += __expf(lg - mx[r]);
      } else {
        sm[r] = sm[r] * __expf(mx[r] - lg) + 1.f;
        mx[r] = lg;
      }
    }
  }

#pragma unroll
  for (int off = 1; off <= 8; off <<= 1) {
#pragma unroll
    for (int r = 0; r < 4; ++r) {
      float om = __shfl_xor(mx[r], off, 64);
      float os = __shfl_xor(sm[r], off, 64);
      float ot = __shfl_xor(tg[r], off, 64);
      float nm = fmaxf(mx[r], om);
      sm[r] = sm[r] * __expf(mx[r] - nm) + os * __expf(om - nm);
      mx[r] = nm;
      tg[r] += ot;
    }
  }
  if ((l & 15) == 0) {
    int idx = (t * 2 + half) * 64 + m0 + ((l >> 4) << 2);
#pragma unroll
    for (int r = 0; r < 4; ++r) {
      pmx[idx + r] = mx[r]; psm[idx + r] = sm[r]; ptg[idx + r] = tg[r];
    }
  }
}

// ---------------- merge halves, per-row loss, sum ----------------
__global__ __launch_bounds__(256) void cemerge_k(const float* __restrict__ pmx,
                                                 const float* __restrict__ psm,
                                                 const float* __restrict__ ptg,
                                                 float* __restrict__ accum) {
  int g = blockIdx.x * 256 + threadIdx.x;   // 0..8191
  int t = g >> 6, row = g & 63;
  int i0 = (t * 2) * 64 + row, i1 = (t * 2 + 1) * 64 + row;
  float m0 = pmx[i0], m1 = pmx[i1];
  float M = fmaxf(m0, m1);
  float S = psm[i0] * __expf(m0 - M) + psm[i1] * __expf(m1 - M);
  float loss = M + logf(S) - (ptg[i0] + ptg[i1]);
#pragma unroll
  for (int off = 32; off >= 1; off >>= 1)
    loss += __shfl_xor(loss, off, 64);
  if ((threadIdx.x & 63) == 0) atomicAdd(accum, loss);
}

__global__ void finish_k(const float* __restrict__ accum, float* __restrict__ out) {
  out[0] = accum[0] * (1.f / (float)NROW);
}

// ---------------- launcher ----------------
extern "C" void kernel_launch(void* const* d_in, const int* in_sizes, int n_in,
                              void* d_out, int out_size, void* d_ws, size_t ws_size,
                              hipStream_t stream) {
  const int*   ids  = (const int*)  d_in[0];
  const int*   tgts = (const int*)  d_in[1];
  const float* emb  = (const float*)d_in[2];
  const float* W1   = (const float*)d_in[3];
  const float* b1   = (const float*)d_in[4];
  const float* W2   = (const float*)d_in[5];
  const float* b2   = (const float*)d_in[6];
  const float* Wv   = (const float*)d_in[7];
  const float* bv   = (const float*)d_in[8];
  float* out = (float*)d_out;

  // ws layout (bytes), xb and Wvb share one region (xb dead before wvtrans):
  char* ws = (char*)d_ws;
  unsigned short* G1    = (unsigned short*)(ws);                 // 33,554,432
  unsigned short* outsb = (unsigned short*)(ws + 33554432);      //  8,388,608
  unsigned short* h1g   = (unsigned short*)(ws + 41943040);      //    131,072
  unsigned short* h2g   = (unsigned short*)(ws + 42074112);      //    131,072
  unsigned short* xb    = (unsigned short*)(ws + 42205184);      //  8,388,608 (union)
  unsigned short* Wvb   = (unsigned short*)(ws + 42205184);      //  8,192,000 (union)
  unsigned short* W1b   = (unsigned short*)(ws + 50593792);      //  2,097,152
  float*          pmx   = (float*)         (ws + 52690944);      //     65,536
  float*          psm   = (float*)         (ws + 52756480);      //     65,536
  float*          ptg   = (float*)         (ws + 52822016);      //     65,536
  float*          accum = (float*)         (ws + 52887552);      //          4
  int*            flags = (int*)           (ws + 52887556);      //  128*16*4 = 8192

  // zero h-states (65,536 f32) and accum+flags (1 + 2048 f32-equivalents)
  zero_k<<<256, 256, 0, stream>>>((float*)h1g, 65536);
  zero_k<<<9, 256, 0, stream>>>(accum, 2049);

  xgather_k<<<2048, 256, 0, stream>>>(ids, emb, xb);
  trans_k<<<256, 256, 0, stream>>>(W1, W1b, NG, 32);         // W1[0:512,:] -> W1b
  gemm1mm_k<<<256, 256, 0, stream>>>(xb, W1b, b1, G1);
  trans_k<<<1000, 256, 0, stream>>>(Wv, Wvb, V_SIZE, 125);   // Wv -> Wvb (after gemm1)

  {
    void* args[] = { (void*)&W1, (void*)&W2, (void*)&b2, (void*)&G1,
                     (void*)&h1g, (void*)&h2g, (void*)&outsb, (void*)&flags };
    hipError_t e = hipLaunchCooperativeKernel((const void*)recur_k,
                                              dim3(RBLK), dim3(RTH),
                                              args, 0, stream);
    if (e != hipSuccess) {
      recur_k<<<dim3(RBLK), dim3(RTH), 0, stream>>>(W1, W2, b2, G1, h1g, h2g,
                                                    outsb, flags);
    }
  }

  ce_mfma_k<<<256, 256, 0, stream>>>(outsb, Wvb, bv, tgts, pmx, psm, ptg);
  cemerge_k<<<32, 256, 0, stream>>>(pmx, psm, ptg, accum);
  finish_k<<<1, 1, 0, stream>>>(accum, out);
}